// Round 6
// baseline (246.522 us; speedup 1.0000x reference)
//
#include <hip/hip_runtime.h>

// y[b, c*128+i] = sum_j x[b,c,j]*(R-Q)[i,j] + sum_j S[b,j]*Q[i,j],  S = sum_c x[b,c,:]
// R6: + 1-deep register double-buffer prefetch of the next x-row (async-STAGE
//     split): issue row rr+1's 8 nontemporal loads before row rr's pack/MFMA,
//     so HBM latency hides under the 64-MFMA compute phase. rr-loop fully
//     unrolled -> all xa[] indices compile-time (no scratch). ~110 VGPR < 128.

typedef __attribute__((ext_vector_type(4))) float  float4v;
typedef __attribute__((ext_vector_type(4))) float  f32x4;
typedef __attribute__((ext_vector_type(8))) short  short8;

__device__ inline unsigned short f2bf(float f) {
    unsigned u = __builtin_bit_cast(unsigned, f);
    u = (u + 0x7fffu + ((u >> 16) & 1u)) >> 16;   // round-to-nearest-even
    return (unsigned short)u;
}

__global__ void
__attribute__((amdgpu_flat_work_group_size(512, 512), amdgpu_waves_per_eu(4, 4)))
cmix_kernel(const float* __restrict__ x, const float* __restrict__ R,
            const float* __restrict__ Q, float* __restrict__ y) {
    // B-fragments in MFMA order: W*[kk][n][lane] elem j = W[n*16+(lane&15)][kk*32+(lane>>4)*8+j]
    __shared__ short8 WA[4][8][64];   // R - Q   (diagonal blocks)
    __shared__ short8 WB[4][8][64];   // Q       (S term)

    const int tid = threadIdx.x;

    // ---- stage both weight arrays (all 512 WGs resident at t=0 -> L2-hot) ----
    for (int idx = tid; idx < 4096; idx += 512) {
        const int l  = idx & 63;
        const int n  = (idx >> 6) & 7;
        const int kk = idx >> 9;                  // 0..7 ; 0-3 -> WA, 4-7 -> WB
        const int i  = n * 16 + (l & 15);         // output feature
        const int k  = (kk & 3) * 32 + (l >> 4) * 8;
        const float4v q0 = *(const float4v*)(Q + i * 128 + k);
        const float4v q1 = *(const float4v*)(Q + i * 128 + k + 4);
        short8 v;
        if (kk < 4) {
            const float4v r0 = *(const float4v*)(R + i * 128 + k);
            const float4v r1 = *(const float4v*)(R + i * 128 + k + 4);
#pragma unroll
            for (int j = 0; j < 4; ++j) {
                v[j]     = (short)f2bf(r0[j] - q0[j]);
                v[4 + j] = (short)f2bf(r1[j] - q1[j]);
            }
            WA[kk][n][l] = v;
        } else {
#pragma unroll
            for (int j = 0; j < 4; ++j) {
                v[j]     = (short)f2bf(q0[j]);
                v[4 + j] = (short)f2bf(q1[j]);
            }
            WB[kk - 4][n][l] = v;
        }
    }
    __syncthreads();

    const int lane = tid & 63;
    const int w    = tid >> 6;    // 0..7
    const int c16  = lane & 15;   // channel (A-row / M), also B/D column
    const int g    = lane >> 4;   // k-group
    const int s4   = lane & 3;
    const int a4   = (lane >> 2) & 3;

    const int b_base = blockIdx.x * 32 + w * 4;
    const float* xrow0 = x + (size_t)b_base * 2048 + c16 * 128 + g * 8;

    // double-buffered x fragments; all indices compile-time after full unroll
    float4v xa[2][4][2];

    // ---- prologue: load row 0 ----
#pragma unroll
    for (int t = 0; t < 4; ++t) {
        const float* p = xrow0 + t * 32;
        xa[0][t][0] = __builtin_nontemporal_load((const float4v*)p);
        xa[0][t][1] = __builtin_nontemporal_load((const float4v*)p + 1);
    }

#pragma unroll
    for (int rr = 0; rr < 4; ++rr) {
        const int cur = rr & 1;
        const int nxt = cur ^ 1;

        // ---- issue next row's loads BEFORE this row's compute ----
        if (rr < 3) {
            const float* xrn = xrow0 + (size_t)(rr + 1) * 2048;
#pragma unroll
            for (int t = 0; t < 4; ++t) {
                const float* p = xrn + t * 32;
                xa[nxt][t][0] = __builtin_nontemporal_load((const float4v*)p);
                xa[nxt][t][1] = __builtin_nontemporal_load((const float4v*)p + 1);
            }
        }

        // ---- pack current row to bf16 fragments ----
        short8 afr[4];
#pragma unroll
        for (int t = 0; t < 4; ++t) {
            short8 av;
#pragma unroll
            for (int j = 0; j < 4; ++j) {
                av[j]     = (short)f2bf(xa[cur][t][0][j]);
                av[4 + j] = (short)f2bf(xa[cur][t][1][j]);
            }
            afr[t] = av;
        }

        // ---- per n-tile: ad = x·(R-Q)^T, aq = x·Q^T ; Sq = row-sum(aq) ----
        float* yr = y + (size_t)(b_base + rr) * 2048;
#pragma unroll 2
        for (int n = 0; n < 8; ++n) {
            f32x4 ad = (f32x4){0.f, 0.f, 0.f, 0.f};
            f32x4 aq = (f32x4){0.f, 0.f, 0.f, 0.f};
#pragma unroll
            for (int kk = 0; kk < 4; ++kk) {
                ad = __builtin_amdgcn_mfma_f32_16x16x32_bf16(afr[kk], WA[kk][n][lane], ad, 0, 0, 0);
                aq = __builtin_amdgcn_mfma_f32_16x16x32_bf16(afr[kk], WB[kk][n][lane], aq, 0, 0, 0);
            }
            // Sq[col=c16] = sum over all 16 rows of aq tile (rows live across g,r)
            float sq = (aq[0] + aq[1]) + (aq[2] + aq[3]);
            sq += __shfl_xor(sq, 16, 64);
            sq += __shfl_xor(sq, 32, 64);

            f32x4 v;
#pragma unroll
            for (int r = 0; r < 4; ++r) v[r] = ad[r] + sq;

            // 4x4 lane transpose within quads -> dwordx4 store
            {   // stage 1: exchange across lane bit 0, reg pairs (0,1) and (2,3)
                float A0 = v[0], B0 = v[1], A1 = v[2], B1 = v[3];
                float o0 = __shfl_xor((lane & 1) ? A0 : B0, 1, 64);
                float o1 = __shfl_xor((lane & 1) ? A1 : B1, 1, 64);
                if (lane & 1) { v[0] = o0; v[2] = o1; }
                else          { v[1] = o0; v[3] = o1; }
            }
            {   // stage 2: exchange across lane bit 1, reg pairs (0,2) and (1,3)
                float A0 = v[0], B0 = v[2], A1 = v[1], B1 = v[3];
                float o0 = __shfl_xor((lane & 2) ? A0 : B0, 2, 64);
                float o1 = __shfl_xor((lane & 2) ? A1 : B1, 2, 64);
                if (lane & 2) { v[0] = o0; v[1] = o1; }
                else          { v[2] = o0; v[3] = o1; }
            }
            __builtin_nontemporal_store(v, (float4v*)(yr + (g * 4 + s4) * 128 + n * 16 + a4 * 4));
        }
    }
}

extern "C" void kernel_launch(void* const* d_in, const int* in_sizes, int n_in,
                              void* d_out, int out_size, void* d_ws, size_t ws_size,
                              hipStream_t stream) {
    const float* x = (const float*)d_in[0];
    const float* R = (const float*)d_in[1];
    const float* Q = (const float*)d_in[2];
    float* y = (float*)d_out;
    // 32 rows per WG (8 waves x 4 rows), grid = 512 (2 WG/CU, all resident)
    hipLaunchKernelGGL(cmix_kernel, dim3(512), dim3(512), 0, stream, x, R, Q, y);
}